// Round 1
// baseline (726.648 us; speedup 1.0000x reference)
//
#include <hip/hip_runtime.h>
#include <hip/hip_bf16.h>

// ---------------- CSR build ----------------

__global__ __launch_bounds__(256) void k_hist(const int* __restrict__ col, int E,
                                              int* __restrict__ cnt) {
    for (int e = blockIdx.x * blockDim.x + threadIdx.x; e < E;
         e += gridDim.x * blockDim.x)
        atomicAdd(&cnt[col[e]], 1);
}

__global__ __launch_bounds__(256) void k_scan_part(const int* __restrict__ cnt, int N,
                                                   int* __restrict__ bsum) {
    int i0 = blockIdx.x * 1024 + threadIdx.x * 4;
    int s = 0;
#pragma unroll
    for (int j = 0; j < 4; ++j) {
        int i = i0 + j;
        if (i < N) s += cnt[i];
    }
#pragma unroll
    for (int off = 32; off; off >>= 1) s += __shfl_down(s, off);
    __shared__ int red[4];
    int lane = threadIdx.x & 63, w = threadIdx.x >> 6;
    if (lane == 0) red[w] = s;
    __syncthreads();
    if (threadIdx.x == 0) bsum[blockIdx.x] = red[0] + red[1] + red[2] + red[3];
}

// single block, 128 threads; requires nb <= 128
__global__ void k_scan_top(int* bsum, int nb) {
    __shared__ int tmp[128];
    int t = threadIdx.x;
    int orig = (t < nb) ? bsum[t] : 0;
    tmp[t] = orig;
    __syncthreads();
    for (int off = 1; off < 128; off <<= 1) {
        int v = (t >= off) ? tmp[t - off] : 0;
        __syncthreads();
        tmp[t] += v;
        __syncthreads();
    }
    if (t < nb) bsum[t] = tmp[t] - orig;  // exclusive
}

__global__ __launch_bounds__(256) void k_scan_final(
    const int* __restrict__ cnt, const int* __restrict__ bsum, int N, int E,
    int* __restrict__ offs, int* __restrict__ cursor, float* __restrict__ dinv) {
    int t = threadIdx.x;
    int i0 = blockIdx.x * 1024 + t * 4;
    int x[4];
#pragma unroll
    for (int j = 0; j < 4; ++j) {
        int i = i0 + j;
        x[j] = (i < N) ? cnt[i] : 0;
    }
    int tot = x[0] + x[1] + x[2] + x[3];
    int run = tot;
    int lane = t & 63, w = t >> 6;
#pragma unroll
    for (int off = 1; off < 64; off <<= 1) {
        int v = __shfl_up(run, off);
        if (lane >= off) run += v;
    }
    __shared__ int wsum[4];
    if (lane == 63) wsum[w] = run;
    __syncthreads();
    int base = bsum[blockIdx.x];
    for (int u = 0; u < w; ++u) base += wsum[u];
    base += run - tot;  // exclusive prefix for this thread's first element
#pragma unroll
    for (int j = 0; j < 4; ++j) {
        int i = i0 + j;
        if (i < N) {
            offs[i] = base;
            cursor[i] = base;
            dinv[i] = rsqrtf((float)(x[j] + 1));  // +1 self loop; always > 0
            base += x[j];
        }
    }
    if (blockIdx.x == 0 && t == 0) offs[N] = E;
}

__global__ __launch_bounds__(256) void k_scatter(const int* __restrict__ ei, int E,
                                                 int* __restrict__ cursor,
                                                 int* __restrict__ csr) {
    for (int e = blockIdx.x * blockDim.x + threadIdx.x; e < E;
         e += gridDim.x * blockDim.x) {
        int c = ei[E + e];                 // target
        int p = atomicAdd(&cursor[c], 1);
        csr[p] = ei[e];                    // source
    }
}

// ---------------- graph boundaries (batch is sorted) ----------------

__global__ __launch_bounds__(256) void k_bounds(const int* __restrict__ batch, int N,
                                                int G, int* __restrict__ gstart) {
    for (int i = blockIdx.x * blockDim.x + threadIdx.x; i < N;
         i += gridDim.x * blockDim.x) {
        int b = batch[i];
        int prev = (i == 0) ? -1 : batch[i - 1];
        for (int g = prev + 1; g <= b; ++g) gstart[g] = i;
        if (i == N - 1)
            for (int g = b + 1; g <= G; ++g) gstart[g] = N;
    }
}

// ---------------- GEMM: out[i,:] = (A[i,:] @ W) * dinv[i]   (W is [K,128]) ----------------

__global__ __launch_bounds__(256) void k_gemm_scale(
    const float* __restrict__ A, const float* __restrict__ W,
    const float* __restrict__ dinv, float* __restrict__ out, int N, int K) {
    __shared__ float As[64][36];    // BM=64, BK=32, padded stride 36 (16B aligned)
    __shared__ float Ws[32][132];   // BK=32, BN=128, padded stride 132 (16B aligned)
    const int tid = threadIdx.x;
    const int row0 = blockIdx.x * 64;
    const int tc = tid & 15;        // 16 col-groups of 8
    const int tr = tid >> 4;        // 16 row-groups of 4
    float acc[4][8] = {};
    for (int kb = 0; kb < K; kb += 32) {
        // stage A tile 64x32 (512 float4, 2 per thread)
#pragma unroll
        for (int u = 0; u < 2; ++u) {
            int s = u * 256 + tid;
            int r = s >> 3, c4 = (s & 7) << 2;
            float4 v = make_float4(0.f, 0.f, 0.f, 0.f);
            int gr = row0 + r;
            if (gr < N) v = *(const float4*)(A + (size_t)gr * K + kb + c4);
            *(float4*)(&As[r][c4]) = v;
        }
        // stage W tile 32x128 (1024 float4, 4 per thread)
#pragma unroll
        for (int u = 0; u < 4; ++u) {
            int s = u * 256 + tid;
            int r = s >> 5, c4 = (s & 31) << 2;
            *(float4*)(&Ws[r][c4]) = *(const float4*)(W + (size_t)(kb + r) * 128 + c4);
        }
        __syncthreads();
#pragma unroll
        for (int k = 0; k < 32; ++k) {
            float av[4];
#pragma unroll
            for (int i = 0; i < 4; ++i) av[i] = As[tr * 4 + i][k];
            float4 w0 = *(const float4*)(&Ws[k][tc * 8]);
            float4 w1 = *(const float4*)(&Ws[k][tc * 8 + 4]);
            float wv[8] = {w0.x, w0.y, w0.z, w0.w, w1.x, w1.y, w1.z, w1.w};
#pragma unroll
            for (int i = 0; i < 4; ++i)
#pragma unroll
                for (int j = 0; j < 8; ++j)
                    acc[i][j] = fmaf(av[i], wv[j], acc[i][j]);
        }
        __syncthreads();
    }
#pragma unroll
    for (int i = 0; i < 4; ++i) {
        int gr = row0 + tr * 4 + i;
        if (gr < N) {
            float dv = dinv[gr];
            float4 o0 = make_float4(acc[i][0] * dv, acc[i][1] * dv, acc[i][2] * dv,
                                    acc[i][3] * dv);
            float4 o1 = make_float4(acc[i][4] * dv, acc[i][5] * dv, acc[i][6] * dv,
                                    acc[i][7] * dv);
            *(float4*)(out + (size_t)gr * 128 + tc * 8) = o0;
            *(float4*)(out + (size_t)gr * 128 + tc * 8 + 4) = o1;
        }
    }
}

// ---------------- SpMM: out[c,:] = relu(dinv[c]*(hs[c,:] + sum_{r in in(c)} hs[r,:]) + b) ----------------

__global__ __launch_bounds__(256) void k_spmm(
    const float2* __restrict__ hs2, const int* __restrict__ csr,
    const int* __restrict__ offs, const float* __restrict__ dinv,
    const float* __restrict__ bias, float2* __restrict__ out, int N) {
    int node = blockIdx.x * 4 + (threadIdx.x >> 6);  // one wave per node
    int lane = threadIdx.x & 63;
    if (node >= N) return;
    int beg = offs[node], end = offs[node + 1];
    float2 acc = hs2[(size_t)node * 64 + lane];      // self loop
    int i = beg;
    for (; i + 4 <= end; i += 4) {                   // 4 gathers in flight
        int r0 = csr[i], r1 = csr[i + 1], r2 = csr[i + 2], r3 = csr[i + 3];
        float2 f0 = hs2[(size_t)r0 * 64 + lane];
        float2 f1 = hs2[(size_t)r1 * 64 + lane];
        float2 f2 = hs2[(size_t)r2 * 64 + lane];
        float2 f3 = hs2[(size_t)r3 * 64 + lane];
        acc.x += (f0.x + f1.x) + (f2.x + f3.x);
        acc.y += (f0.y + f1.y) + (f2.y + f3.y);
    }
    for (; i < end; ++i) {
        int r = csr[i];
        float2 f = hs2[(size_t)r * 64 + lane];
        acc.x += f.x;
        acc.y += f.y;
    }
    float dv = dinv[node];
    float2 b = ((const float2*)bias)[lane];
    float2 o;
    o.x = fmaxf(fmaf(acc.x, dv, b.x), 0.f);
    o.y = fmaxf(fmaf(acc.y, dv, b.y), 0.f);
    out[(size_t)node * 64 + lane] = o;
}

// ---------------- pooling ----------------

__global__ void k_pool(const float* __restrict__ h, const int* __restrict__ gstart,
                       float* __restrict__ psum, int G) {
    int g = blockIdx.x >> 3, sl = blockIdx.x & 7;   // 8 blocks per graph
    int r0 = gstart[g], r1 = gstart[g + 1];
    float s = 0.f;
    for (int r = r0 + sl; r < r1; r += 8) s += h[(size_t)r * 128 + threadIdx.x];
    atomicAdd(&psum[g * 128 + threadIdx.x], s);
}

__global__ void k_div(const float* __restrict__ psum, const int* __restrict__ gstart,
                      float* __restrict__ out, int total) {
    int i = blockIdx.x * blockDim.x + threadIdx.x;
    if (i < total) {
        int g = i >> 7;
        float c = (float)(gstart[g + 1] - gstart[g]);
        out[i] = psum[i] / fmaxf(c, 1.f);
    }
}

// ---------------- launch ----------------

extern "C" void kernel_launch(void* const* d_in, const int* in_sizes, int n_in,
                              void* d_out, int out_size, void* d_ws, size_t ws_size,
                              hipStream_t stream) {
    const float* x     = (const float*)d_in[0];
    const int*   ei    = (const int*)d_in[1];   // [2,E]: rows then cols
    const int*   batch = (const int*)d_in[2];
    const float* W1    = (const float*)d_in[3];
    const float* b1    = (const float*)d_in[4];
    const float* W2    = (const float*)d_in[5];
    const float* b2    = (const float*)d_in[6];
    float* outp = (float*)d_out;

    const int N = in_sizes[2];
    const int E = in_sizes[1] / 2;
    const int D = in_sizes[0] / N;   // 512
    const int H = in_sizes[4];       // 128
    const int G = out_size / H;      // 64

    char* ws = (char*)d_ws;
    size_t off = 0;
    auto alloc = [&](size_t bytes) -> char* {
        char* p = ws + off;
        off = (off + bytes + 255) & ~(size_t)255;
        return p;
    };
    int*   cnt    = (int*)alloc((size_t)N * 4);
    float* dinv   = (float*)alloc((size_t)N * 4);
    int*   offs   = (int*)alloc((size_t)(N + 1) * 4);
    int*   cursor = (int*)alloc((size_t)N * 4);
    int*   bsum   = (int*)alloc(128 * 4);
    int*   gstart = (int*)alloc((size_t)(G + 1) * 4);
    float* psum   = (float*)alloc((size_t)G * H * 4);
    int*   csr    = (int*)alloc((size_t)E * 4);
    float* hs     = (float*)alloc((size_t)N * H * 4);
    float* h1     = (float*)alloc((size_t)N * H * 4);
    (void)ws_size; (void)n_in;

    hipMemsetAsync(cnt, 0, (size_t)N * 4, stream);
    hipMemsetAsync(psum, 0, (size_t)G * H * 4, stream);

    int nb = (N + 1023) / 1024;  // 98 <= 128

    k_hist<<<2048, 256, 0, stream>>>(ei + E, E, cnt);
    k_scan_part<<<nb, 256, 0, stream>>>(cnt, N, bsum);
    k_scan_top<<<1, 128, 0, stream>>>(bsum, nb);
    k_scan_final<<<nb, 256, 0, stream>>>(cnt, bsum, N, E, offs, cursor, dinv);
    k_scatter<<<2048, 256, 0, stream>>>(ei, E, cursor, csr);
    k_bounds<<<(N + 255) / 256, 256, 0, stream>>>(batch, N, G, gstart);

    // layer 1
    k_gemm_scale<<<(N + 63) / 64, 256, 0, stream>>>(x, W1, dinv, hs, N, D);
    k_spmm<<<(N + 3) / 4, 256, 0, stream>>>((const float2*)hs, csr, offs, dinv, b1,
                                            (float2*)h1, N);
    // layer 2
    k_gemm_scale<<<(N + 63) / 64, 256, 0, stream>>>(h1, W2, dinv, hs, N, H);
    k_spmm<<<(N + 3) / 4, 256, 0, stream>>>((const float2*)hs, csr, offs, dinv, b2,
                                            (float2*)h1, N);
    // pool
    k_pool<<<G * 8, 128, 0, stream>>>(h1, gstart, psum, G);
    k_div<<<(G * H + 255) / 256, 256, 0, stream>>>(psum, gstart, outp, G * H);
}

// Round 2
// 494.440 us; speedup vs baseline: 1.4696x; 1.4696x over previous
//
#include <hip/hip_runtime.h>
#include <hip/hip_bf16.h>

typedef __attribute__((ext_vector_type(8))) short short8;
typedef __attribute__((ext_vector_type(4))) float f32x4;

__device__ __forceinline__ ushort f2b(float f) {
    union { float f; uint u; } v; v.f = f;
    uint u = v.u;
    u += 0x7fffu + ((u >> 16) & 1u);   // RNE
    return (ushort)(u >> 16);
}
__device__ __forceinline__ float blo(uint u) { return __uint_as_float(u << 16); }
__device__ __forceinline__ float bhi(uint u) { return __uint_as_float(u & 0xffff0000u); }

// ---------------- CSR build ----------------

__global__ __launch_bounds__(256) void k_hist(const int* __restrict__ col, int E,
                                              int* __restrict__ cnt) {
    for (int e = blockIdx.x * blockDim.x + threadIdx.x; e < E;
         e += gridDim.x * blockDim.x)
        atomicAdd(&cnt[col[e]], 1);
}

__global__ __launch_bounds__(256) void k_scan_part(const int* __restrict__ cnt, int N,
                                                   int* __restrict__ bsum) {
    int i0 = blockIdx.x * 1024 + threadIdx.x * 4;
    int s = 0;
#pragma unroll
    for (int j = 0; j < 4; ++j) {
        int i = i0 + j;
        if (i < N) s += cnt[i];
    }
#pragma unroll
    for (int off = 32; off; off >>= 1) s += __shfl_down(s, off);
    __shared__ int red[4];
    int lane = threadIdx.x & 63, w = threadIdx.x >> 6;
    if (lane == 0) red[w] = s;
    __syncthreads();
    if (threadIdx.x == 0) bsum[blockIdx.x] = red[0] + red[1] + red[2] + red[3];
}

// single block, 128 threads; requires nb <= 128
__global__ void k_scan_top(int* bsum, int nb) {
    __shared__ int tmp[128];
    int t = threadIdx.x;
    int orig = (t < nb) ? bsum[t] : 0;
    tmp[t] = orig;
    __syncthreads();
    for (int off = 1; off < 128; off <<= 1) {
        int v = (t >= off) ? tmp[t - off] : 0;
        __syncthreads();
        tmp[t] += v;
        __syncthreads();
    }
    if (t < nb) bsum[t] = tmp[t] - orig;  // exclusive
}

__global__ __launch_bounds__(256) void k_scan_final(
    const int* __restrict__ cnt, const int* __restrict__ bsum, int N, int E,
    int* __restrict__ offs, int* __restrict__ cursor, float* __restrict__ dinv) {
    int t = threadIdx.x;
    int i0 = blockIdx.x * 1024 + t * 4;
    int x[4];
#pragma unroll
    for (int j = 0; j < 4; ++j) {
        int i = i0 + j;
        x[j] = (i < N) ? cnt[i] : 0;
    }
    int tot = x[0] + x[1] + x[2] + x[3];
    int run = tot;
    int lane = t & 63, w = t >> 6;
#pragma unroll
    for (int off = 1; off < 64; off <<= 1) {
        int v = __shfl_up(run, off);
        if (lane >= off) run += v;
    }
    __shared__ int wsum[4];
    if (lane == 63) wsum[w] = run;
    __syncthreads();
    int base = bsum[blockIdx.x];
    for (int u = 0; u < w; ++u) base += wsum[u];
    base += run - tot;
#pragma unroll
    for (int j = 0; j < 4; ++j) {
        int i = i0 + j;
        if (i < N) {
            offs[i] = base;
            cursor[i] = base;
            dinv[i] = rsqrtf((float)(x[j] + 1));
            base += x[j];
        }
    }
    if (blockIdx.x == 0 && t == 0) offs[N] = E;
}

__global__ __launch_bounds__(256) void k_scatter(const int* __restrict__ ei, int E,
                                                 int* __restrict__ cursor,
                                                 int* __restrict__ csr) {
    for (int e = blockIdx.x * blockDim.x + threadIdx.x; e < E;
         e += gridDim.x * blockDim.x) {
        int c = ei[E + e];
        int p = atomicAdd(&cursor[c], 1);
        csr[p] = ei[e];
    }
}

__global__ __launch_bounds__(256) void k_bounds(const int* __restrict__ batch, int N,
                                                int G, int* __restrict__ gstart) {
    for (int i = blockIdx.x * blockDim.x + threadIdx.x; i < N;
         i += gridDim.x * blockDim.x) {
        int b = batch[i];
        int prev = (i == 0) ? -1 : batch[i - 1];
        for (int g = prev + 1; g <= b; ++g) gstart[g] = i;
        if (i == N - 1)
            for (int g = b + 1; g <= G; ++g) gstart[g] = N;
    }
}

// ---------------- weight convert + transpose: Wt[n][k] = bf16(W[k][n]), n<128 ----------------

__global__ void k_cvtW(const float* __restrict__ W, ushort* __restrict__ Wt, int K) {
    int o = blockIdx.x * 256 + threadIdx.x;
    if (o < 128 * K) {
        int n = o / K, k = o - n * K;
        Wt[o] = f2b(W[(size_t)k * 128 + n]);
    }
}

// ---------------- MFMA GEMM: out[i,:] = bf16((A[i,:] @ Wt^T) * dinv[i]) ----------------
// A: fp32 [N][K] (ABF16=0, converted on the fly) or bf16 [N][K] (ABF16=1).
// Wt: bf16 [128][K] (pre-transposed).  BM=128, BN=128, BK=64, 4 waves x 32 rows.

template <int ABF16>
__global__ __launch_bounds__(256) void k_gemm_mfma(
    const void* __restrict__ Ap, const ushort* __restrict__ Wt,
    const float* __restrict__ dinv, ushort* __restrict__ outb, int N, int K) {
    __shared__ ushort As[128][72];   // stride 144B: even bank spread
    __shared__ ushort Bs[128][72];
    const int tid = threadIdx.x;
    const int row0 = blockIdx.x * 128;
    const int w = tid >> 6, l = tid & 63;
    const int lr = l & 15, lk = l >> 4;
    f32x4 acc[2][8] = {};
    for (int kb = 0; kb < K; kb += 64) {
        if constexpr (ABF16 == 0) {
            const float* A = (const float*)Ap;
#pragma unroll
            for (int u = 0; u < 8; ++u) {
                int s = u * 256 + tid;
                int r = s >> 4, c4 = s & 15;
                int gr = row0 + r;
                float4 v = make_float4(0.f, 0.f, 0.f, 0.f);
                if (gr < N) v = *(const float4*)(A + (size_t)gr * K + kb + c4 * 4);
                ushort4 b;
                b.x = f2b(v.x); b.y = f2b(v.y); b.z = f2b(v.z); b.w = f2b(v.w);
                *(ushort4*)&As[r][c4 * 4] = b;
            }
        } else {
            const ushort* A = (const ushort*)Ap;
#pragma unroll
            for (int u = 0; u < 4; ++u) {
                int s = u * 256 + tid;
                int r = s >> 3, c8 = s & 7;
                int gr = row0 + r;
                uint4 v = make_uint4(0u, 0u, 0u, 0u);
                if (gr < N) v = *(const uint4*)(A + (size_t)gr * K + kb + c8 * 8);
                *(uint4*)&As[r][c8 * 8] = v;
            }
        }
#pragma unroll
        for (int u = 0; u < 4; ++u) {
            int s = u * 256 + tid;
            int r = s >> 3, c8 = s & 7;
            *(uint4*)&Bs[r][c8 * 8] = *(const uint4*)(Wt + (size_t)r * K + kb + c8 * 8);
        }
        __syncthreads();
        const int wr0 = w * 32;
#pragma unroll
        for (int ks = 0; ks < 2; ++ks) {
            short8 a0 = *(const short8*)&As[wr0 + lr][ks * 32 + lk * 8];
            short8 a1 = *(const short8*)&As[wr0 + 16 + lr][ks * 32 + lk * 8];
#pragma unroll
            for (int nf = 0; nf < 8; ++nf) {
                short8 bf = *(const short8*)&Bs[nf * 16 + lr][ks * 32 + lk * 8];
                acc[0][nf] = __builtin_amdgcn_mfma_f32_16x16x32_bf16(a0, bf, acc[0][nf], 0, 0, 0);
                acc[1][nf] = __builtin_amdgcn_mfma_f32_16x16x32_bf16(a1, bf, acc[1][nf], 0, 0, 0);
            }
        }
        __syncthreads();
    }
#pragma unroll
    for (int mf = 0; mf < 2; ++mf) {
#pragma unroll
        for (int r = 0; r < 4; ++r) {
            int row = row0 + w * 32 + mf * 16 + lk * 4 + r;
            if (row < N) {
                float dv = dinv[row];
#pragma unroll
                for (int nf = 0; nf < 8; ++nf)
                    outb[(size_t)row * 128 + nf * 16 + lr] = f2b(acc[mf][nf][r] * dv);
            }
        }
    }
}

// ---------------- SpMM (bf16 in/out, fp32 accum): one wave per target node ----------------

__global__ __launch_bounds__(256) void k_spmm(
    const uint* __restrict__ hs, const int* __restrict__ csr,
    const int* __restrict__ offs, const float* __restrict__ dinv,
    const float* __restrict__ bias, uint* __restrict__ outb, int N) {
    int node = blockIdx.x * 4 + (threadIdx.x >> 6);
    int lane = threadIdx.x & 63;
    if (node >= N) return;
    int beg = offs[node], end = offs[node + 1];
    uint u0 = hs[(size_t)node * 64 + lane];          // self loop
    float ax = blo(u0), ay = bhi(u0);
    int i = beg;
    for (; i + 4 <= end; i += 4) {
        int r0 = csr[i], r1 = csr[i + 1], r2 = csr[i + 2], r3 = csr[i + 3];
        uint a = hs[(size_t)r0 * 64 + lane];
        uint b = hs[(size_t)r1 * 64 + lane];
        uint c = hs[(size_t)r2 * 64 + lane];
        uint d = hs[(size_t)r3 * 64 + lane];
        ax += (blo(a) + blo(b)) + (blo(c) + blo(d));
        ay += (bhi(a) + bhi(b)) + (bhi(c) + bhi(d));
    }
    for (; i < end; ++i) {
        uint a = hs[(size_t)csr[i] * 64 + lane];
        ax += blo(a); ay += bhi(a);
    }
    float dv = dinv[node];
    float2 bb = ((const float2*)bias)[lane];
    float ox = fmaxf(fmaf(ax, dv, bb.x), 0.f);
    float oy = fmaxf(fmaf(ay, dv, bb.y), 0.f);
    outb[(size_t)node * 64 + lane] = ((uint)f2b(oy) << 16) | (uint)f2b(ox);
}

// ---------------- pooling ----------------

__global__ void k_pool(const uint* __restrict__ h, const int* __restrict__ gstart,
                       float* __restrict__ psum, int G) {
    int g = blockIdx.x >> 3, sl = blockIdx.x & 7;
    int r0 = gstart[g], r1 = gstart[g + 1];
    int t = threadIdx.x;
    float sx = 0.f, sy = 0.f;
    for (int r = r0 + sl; r < r1; r += 8) {
        uint u = h[(size_t)r * 64 + t];
        sx += blo(u); sy += bhi(u);
    }
    atomicAdd(&psum[g * 128 + 2 * t], sx);
    atomicAdd(&psum[g * 128 + 2 * t + 1], sy);
}

__global__ void k_div(const float* __restrict__ psum, const int* __restrict__ gstart,
                      float* __restrict__ out, int total) {
    int i = blockIdx.x * blockDim.x + threadIdx.x;
    if (i < total) {
        int g = i >> 7;
        float c = (float)(gstart[g + 1] - gstart[g]);
        out[i] = psum[i] / fmaxf(c, 1.f);
    }
}

// ---------------- launch ----------------

extern "C" void kernel_launch(void* const* d_in, const int* in_sizes, int n_in,
                              void* d_out, int out_size, void* d_ws, size_t ws_size,
                              hipStream_t stream) {
    const float* x     = (const float*)d_in[0];
    const int*   ei    = (const int*)d_in[1];
    const int*   batch = (const int*)d_in[2];
    const float* W1    = (const float*)d_in[3];
    const float* b1    = (const float*)d_in[4];
    const float* W2    = (const float*)d_in[5];
    const float* b2    = (const float*)d_in[6];
    float* outp = (float*)d_out;

    const int N = in_sizes[2];
    const int E = in_sizes[1] / 2;
    const int D = in_sizes[0] / N;   // 512
    const int H = in_sizes[4];       // 128
    const int G = out_size / H;      // 64

    char* ws = (char*)d_ws;
    size_t off = 0;
    auto alloc = [&](size_t bytes) -> char* {
        char* p = ws + off;
        off = (off + bytes + 255) & ~(size_t)255;
        return p;
    };
    int*    cnt    = (int*)alloc((size_t)N * 4);
    float*  dinv   = (float*)alloc((size_t)N * 4);
    int*    offs   = (int*)alloc((size_t)(N + 1) * 4);
    int*    cursor = (int*)alloc((size_t)N * 4);
    int*    bsum   = (int*)alloc(128 * 4);
    int*    gstart = (int*)alloc((size_t)(G + 1) * 4);
    float*  psum   = (float*)alloc((size_t)G * H * 4);
    int*    csr    = (int*)alloc((size_t)E * 4);
    ushort* wt1b   = (ushort*)alloc((size_t)H * D * 2);
    ushort* wt2b   = (ushort*)alloc((size_t)H * H * 2);
    ushort* hb0    = (ushort*)alloc((size_t)N * H * 2);  // GEMM out (scaled)
    ushort* hb1    = (ushort*)alloc((size_t)N * H * 2);  // SpMM out
    (void)ws_size; (void)n_in;

    hipMemsetAsync(cnt, 0, (size_t)N * 4, stream);
    hipMemsetAsync(psum, 0, (size_t)G * H * 4, stream);

    int nb = (N + 1023) / 1024;  // <= 128

    k_hist<<<2048, 256, 0, stream>>>(ei + E, E, cnt);
    k_scan_part<<<nb, 256, 0, stream>>>(cnt, N, bsum);
    k_scan_top<<<1, 128, 0, stream>>>(bsum, nb);
    k_scan_final<<<nb, 256, 0, stream>>>(cnt, bsum, N, E, offs, cursor, dinv);
    k_scatter<<<2048, 256, 0, stream>>>(ei, E, cursor, csr);
    k_bounds<<<(N + 255) / 256, 256, 0, stream>>>(batch, N, G, gstart);
    k_cvtW<<<(128 * D + 255) / 256, 256, 0, stream>>>(W1, wt1b, D);
    k_cvtW<<<(128 * H + 255) / 256, 256, 0, stream>>>(W2, wt2b, H);

    int gblocks = (N + 127) / 128;
    // layer 1
    k_gemm_mfma<0><<<gblocks, 256, 0, stream>>>(x, wt1b, dinv, hb0, N, D);
    k_spmm<<<(N + 3) / 4, 256, 0, stream>>>((const uint*)hb0, csr, offs, dinv, b1,
                                            (uint*)hb1, N);
    // layer 2
    k_gemm_mfma<1><<<gblocks, 256, 0, stream>>>(hb1, wt2b, dinv, hb0, N, H);
    k_spmm<<<(N + 3) / 4, 256, 0, stream>>>((const uint*)hb0, csr, offs, dinv, b2,
                                            (uint*)hb1, N);
    // pool
    k_pool<<<G * 8, 64, 0, stream>>>((const uint*)hb1, gstart, psum, G);
    k_div<<<(G * H + 255) / 256, 256, 0, stream>>>(psum, gstart, outp, G * H);
}

// Round 3
// 383.392 us; speedup vs baseline: 1.8953x; 1.2896x over previous
//
#include <hip/hip_runtime.h>
#include <hip/hip_bf16.h>

typedef __attribute__((ext_vector_type(8))) short short8;
typedef __attribute__((ext_vector_type(4))) float f32x4;

__device__ __forceinline__ ushort f2b(float f) {
    union { float f; uint u; } v; v.f = f;
    uint u = v.u;
    u += 0x7fffu + ((u >> 16) & 1u);   // RNE
    return (ushort)(u >> 16);
}
__device__ __forceinline__ float blo(uint u) { return __uint_as_float(u << 16); }
__device__ __forceinline__ float bhi(uint u) { return __uint_as_float(u & 0xffff0000u); }

// ================= CSR build: bucket counting sort =================
// bucket = node >> 10  (NB = ceil(N/1024) <= 128)

__global__ __launch_bounds__(256) void k_bucket_hist(const int* __restrict__ col, int E,
                                                     int NB, int* __restrict__ bcnt) {
    __shared__ int h[128];
    int tid = threadIdx.x;
    if (tid < 128) h[tid] = 0;
    __syncthreads();
    for (int e = blockIdx.x * blockDim.x + tid; e < E; e += gridDim.x * blockDim.x)
        atomicAdd(&h[col[e] >> 10], 1);
    __syncthreads();
    if (tid < NB && h[tid]) atomicAdd(&bcnt[tid], h[tid]);
}

// single block, 128 threads
__global__ void k_scan_buckets(const int* __restrict__ bcnt, int NB,
                               int* __restrict__ boffs, int* __restrict__ bcursor) {
    __shared__ int tmp[128];
    int t = threadIdx.x;
    int orig = (t < NB) ? bcnt[t] : 0;
    tmp[t] = orig;
    __syncthreads();
    for (int off = 1; off < 128; off <<= 1) {
        int v = (t >= off) ? tmp[t - off] : 0;
        __syncthreads();
        tmp[t] += v;
        __syncthreads();
    }
    if (t < NB) {
        int ex = tmp[t] - orig;
        boffs[t] = ex;
        bcursor[t] = ex;
    }
    if (t == 0) boffs[NB] = tmp[127];
}

// scatter edges into bucket-contiguous ebuf; per-block chunk reservation
__global__ __launch_bounds__(256) void k_bucket_scatter(const int* __restrict__ ei, int E,
                                                        int NB, int* __restrict__ bcursor,
                                                        int2* __restrict__ ebuf) {
    __shared__ int h[128], gb[128], lc[128];
    int tid = threadIdx.x;
    if (tid < 128) { h[tid] = 0; lc[tid] = 0; }
    __syncthreads();
    int e0 = blockIdx.x * 2048;
    int r[8], c[8], bk[8];
#pragma unroll
    for (int u = 0; u < 8; ++u) {
        int e = e0 + u * 256 + tid;
        if (e < E) {
            r[u] = ei[e];
            c[u] = ei[E + e];
            bk[u] = c[u] >> 10;
            atomicAdd(&h[bk[u]], 1);
        }
    }
    __syncthreads();
    if (tid < NB && h[tid]) gb[tid] = atomicAdd(&bcursor[tid], h[tid]);
    __syncthreads();
#pragma unroll
    for (int u = 0; u < 8; ++u) {
        int e = e0 + u * 256 + tid;
        if (e < E) {
            int p = gb[bk[u]] + atomicAdd(&lc[bk[u]], 1);
            ebuf[p] = make_int2(r[u], c[u]);
        }
    }
}

// one block per bucket: LDS counting sort -> csr, offs, dinv
__global__ __launch_bounds__(256) void k_bucket_sort(const int2* __restrict__ ebuf,
                                                     const int* __restrict__ boffs,
                                                     int N, int NB, int E,
                                                     int* __restrict__ offs,
                                                     float* __restrict__ dinv,
                                                     int* __restrict__ csr) {
    __shared__ int cnt[1024];
    __shared__ int cur[1024];
    __shared__ int wsum[4];
    int t = threadIdx.x;
    int b = blockIdx.x;
    int node0 = b << 10;
    int nn = min(1024, N - node0);
    for (int i = t; i < nn; i += 256) cnt[i] = 0;
    __syncthreads();
    int e0 = boffs[b], e1 = boffs[b + 1];
    for (int e = e0 + t; e < e1; e += 256) atomicAdd(&cnt[ebuf[e].y - node0], 1);
    __syncthreads();
    // exclusive scan, 4 elements per thread
    int i0 = t * 4;
    int x[4];
#pragma unroll
    for (int j = 0; j < 4; ++j) x[j] = (i0 + j < nn) ? cnt[i0 + j] : 0;
    int tot = x[0] + x[1] + x[2] + x[3];
    int run = tot;
    int lane = t & 63, w = t >> 6;
#pragma unroll
    for (int off = 1; off < 64; off <<= 1) {
        int v = __shfl_up(run, off);
        if (lane >= off) run += v;
    }
    if (lane == 63) wsum[w] = run;
    __syncthreads();
    int base = 0;
    for (int u = 0; u < w; ++u) base += wsum[u];
    base += run - tot;
#pragma unroll
    for (int j = 0; j < 4; ++j) {
        if (i0 + j < nn) {
            int node = node0 + i0 + j;
            offs[node] = e0 + base;
            cur[i0 + j] = base;
            dinv[node] = rsqrtf((float)(x[j] + 1));
            base += x[j];
        }
    }
    __syncthreads();
    for (int e = e0 + t; e < e1; e += 256) {
        int2 rc = ebuf[e];
        int p = atomicAdd(&cur[rc.y - node0], 1);
        csr[e0 + p] = rc.x;
    }
    if (t == 0 && node0 + nn == N) offs[N] = E;
}

// ================= graph boundaries (batch is sorted) =================

__global__ __launch_bounds__(256) void k_bounds(const int* __restrict__ batch, int N,
                                                int G, int* __restrict__ gstart) {
    for (int i = blockIdx.x * blockDim.x + threadIdx.x; i < N;
         i += gridDim.x * blockDim.x) {
        int b = batch[i];
        int prev = (i == 0) ? -1 : batch[i - 1];
        for (int g = prev + 1; g <= b; ++g) gstart[g] = i;
        if (i == N - 1)
            for (int g = b + 1; g <= G; ++g) gstart[g] = N;
    }
}

// ================= weight convert+transpose: Wt[n][k] = bf16(W[k][n]) =================

__global__ void k_cvtW(const float* __restrict__ W, ushort* __restrict__ Wt, int K) {
    int o = blockIdx.x * 256 + threadIdx.x;
    if (o < 128 * K) {
        int n = o / K, k = o - n * K;
        Wt[o] = f2b(W[(size_t)k * 128 + n]);
    }
}

// ================= MFMA GEMM (2-phase pipelined): out = bf16((A@Wt^T)*dinv) =================
// A: fp32 [N][K] (ABF16=0, converted in staging) or bf16 [N][K] (ABF16=1).
// Wt: bf16 [128][K]. BM=128, BN=128, BK=64, 4 waves x 32 rows.

template <int ABF16>
__global__ __launch_bounds__(256) void k_gemm_mfma(
    const void* __restrict__ Ap, const ushort* __restrict__ Wt,
    const float* __restrict__ dinv, ushort* __restrict__ outb, int N, int K) {
    __shared__ ushort As[128][72];
    __shared__ ushort Bs[128][72];
    const int tid = threadIdx.x;
    const int row0 = blockIdx.x * 128;
    const int w = tid >> 6, l = tid & 63;
    const int lr = l & 15, lk = l >> 4;
    f32x4 acc[2][8] = {};
    const int nt = K >> 6;

    float4 pa[8];
    uint4 pa4[4];
    uint4 pb[4];

    auto loadA = [&](int kb) {
        if constexpr (ABF16 == 0) {
            const float* A = (const float*)Ap;
#pragma unroll
            for (int u = 0; u < 8; ++u) {
                int s = u * 256 + tid;
                int r = s >> 4, c4 = s & 15;
                int gr = row0 + r;
                pa[u] = make_float4(0.f, 0.f, 0.f, 0.f);
                if (gr < N) pa[u] = *(const float4*)(A + (size_t)gr * K + kb + c4 * 4);
            }
        } else {
            const ushort* A = (const ushort*)Ap;
#pragma unroll
            for (int u = 0; u < 4; ++u) {
                int s = u * 256 + tid;
                int r = s >> 3, c8 = s & 7;
                int gr = row0 + r;
                pa4[u] = make_uint4(0u, 0u, 0u, 0u);
                if (gr < N) pa4[u] = *(const uint4*)(A + (size_t)gr * K + kb + c8 * 8);
            }
        }
    };
    auto loadB = [&](int kb) {
#pragma unroll
        for (int u = 0; u < 4; ++u) {
            int s = u * 256 + tid;
            int r = s >> 3, c8 = s & 7;
            pb[u] = *(const uint4*)(Wt + (size_t)r * K + kb + c8 * 8);
        }
    };
    auto store = [&]() {
        if constexpr (ABF16 == 0) {
#pragma unroll
            for (int u = 0; u < 8; ++u) {
                int s = u * 256 + tid;
                int r = s >> 4, c4 = s & 15;
                ushort4 bb;
                bb.x = f2b(pa[u].x); bb.y = f2b(pa[u].y);
                bb.z = f2b(pa[u].z); bb.w = f2b(pa[u].w);
                *(ushort4*)&As[r][c4 * 4] = bb;
            }
        } else {
#pragma unroll
            for (int u = 0; u < 4; ++u) {
                int s = u * 256 + tid;
                int r = s >> 3, c8 = s & 7;
                *(uint4*)&As[r][c8 * 8] = pa4[u];
            }
        }
#pragma unroll
        for (int u = 0; u < 4; ++u) {
            int s = u * 256 + tid;
            int r = s >> 3, c8 = s & 7;
            *(uint4*)&Bs[r][c8 * 8] = pb[u];
        }
    };

    loadA(0);
    loadB(0);
    store();
    for (int t = 0; t < nt; ++t) {
        __syncthreads();
        if (t + 1 < nt) { loadA((t + 1) << 6); loadB((t + 1) << 6); }
        const int wr0 = w * 32;
#pragma unroll
        for (int ks = 0; ks < 2; ++ks) {
            short8 a0 = *(const short8*)&As[wr0 + lr][ks * 32 + lk * 8];
            short8 a1 = *(const short8*)&As[wr0 + 16 + lr][ks * 32 + lk * 8];
#pragma unroll
            for (int nf = 0; nf < 8; ++nf) {
                short8 bf = *(const short8*)&Bs[nf * 16 + lr][ks * 32 + lk * 8];
                acc[0][nf] = __builtin_amdgcn_mfma_f32_16x16x32_bf16(a0, bf, acc[0][nf], 0, 0, 0);
                acc[1][nf] = __builtin_amdgcn_mfma_f32_16x16x32_bf16(a1, bf, acc[1][nf], 0, 0, 0);
            }
        }
        __syncthreads();
        if (t + 1 < nt) store();
    }
#pragma unroll
    for (int mf = 0; mf < 2; ++mf) {
#pragma unroll
        for (int r = 0; r < 4; ++r) {
            int row = row0 + w * 32 + mf * 16 + lk * 4 + r;
            if (row < N) {
                float dv = dinv[row];
#pragma unroll
                for (int nf = 0; nf < 8; ++nf)
                    outb[(size_t)row * 128 + nf * 16 + lr] = f2b(acc[mf][nf][r] * dv);
            }
        }
    }
}

// ================= SpMM (bf16 in/out, fp32 accum): one wave per target node =================

__global__ __launch_bounds__(256) void k_spmm(
    const uint* __restrict__ hs, const int* __restrict__ csr,
    const int* __restrict__ offs, const float* __restrict__ dinv,
    const float* __restrict__ bias, uint* __restrict__ outb, int N) {
    int node = blockIdx.x * 4 + (threadIdx.x >> 6);
    int lane = threadIdx.x & 63;
    if (node >= N) return;
    int beg = offs[node], end = offs[node + 1];
    uint u0 = hs[(size_t)node * 64 + lane];  // self loop
    float ax = blo(u0), ay = bhi(u0);
    int i = beg;
    for (; i + 8 <= end; i += 8) {
        int rr[8];
#pragma unroll
        for (int j = 0; j < 8; ++j) rr[j] = csr[i + j];
        uint v[8];
#pragma unroll
        for (int j = 0; j < 8; ++j) v[j] = hs[(size_t)rr[j] * 64 + lane];
#pragma unroll
        for (int j = 0; j < 8; ++j) { ax += blo(v[j]); ay += bhi(v[j]); }
    }
    for (; i + 4 <= end; i += 4) {
        int r0 = csr[i], r1 = csr[i + 1], r2 = csr[i + 2], r3 = csr[i + 3];
        uint a = hs[(size_t)r0 * 64 + lane];
        uint b = hs[(size_t)r1 * 64 + lane];
        uint c = hs[(size_t)r2 * 64 + lane];
        uint d = hs[(size_t)r3 * 64 + lane];
        ax += (blo(a) + blo(b)) + (blo(c) + blo(d));
        ay += (bhi(a) + bhi(b)) + (bhi(c) + bhi(d));
    }
    for (; i < end; ++i) {
        uint a = hs[(size_t)csr[i] * 64 + lane];
        ax += blo(a); ay += bhi(a);
    }
    float dv = dinv[node];
    float2 bb = ((const float2*)bias)[lane];
    float ox = fmaxf(fmaf(ax, dv, bb.x), 0.f);
    float oy = fmaxf(fmaf(ay, dv, bb.y), 0.f);
    outb[(size_t)node * 64 + lane] = ((uint)f2b(oy) << 16) | (uint)f2b(ox);
}

// ================= pooling =================

__global__ void k_pool(const uint* __restrict__ h, const int* __restrict__ gstart,
                       float* __restrict__ psum, int G) {
    int g = blockIdx.x >> 3, sl = blockIdx.x & 7;
    int r0 = gstart[g], r1 = gstart[g + 1];
    int t = threadIdx.x;
    float sx = 0.f, sy = 0.f;
    for (int r = r0 + sl; r < r1; r += 8) {
        uint u = h[(size_t)r * 64 + t];
        sx += blo(u); sy += bhi(u);
    }
    atomicAdd(&psum[g * 128 + 2 * t], sx);
    atomicAdd(&psum[g * 128 + 2 * t + 1], sy);
}

__global__ void k_div(const float* __restrict__ psum, const int* __restrict__ gstart,
                      float* __restrict__ out, int total) {
    int i = blockIdx.x * blockDim.x + threadIdx.x;
    if (i < total) {
        int g = i >> 7;
        float c = (float)(gstart[g + 1] - gstart[g]);
        out[i] = psum[i] / fmaxf(c, 1.f);
    }
}

// ================= launch =================

extern "C" void kernel_launch(void* const* d_in, const int* in_sizes, int n_in,
                              void* d_out, int out_size, void* d_ws, size_t ws_size,
                              hipStream_t stream) {
    const float* x     = (const float*)d_in[0];
    const int*   ei    = (const int*)d_in[1];
    const int*   batch = (const int*)d_in[2];
    const float* W1    = (const float*)d_in[3];
    const float* b1    = (const float*)d_in[4];
    const float* W2    = (const float*)d_in[5];
    const float* b2    = (const float*)d_in[6];
    float* outp = (float*)d_out;

    const int N = in_sizes[2];
    const int E = in_sizes[1] / 2;
    const int D = in_sizes[0] / N;   // 512
    const int H = in_sizes[4];       // 128
    const int G = out_size / H;      // 64
    const int NB = (N + 1023) >> 10; // <= 128

    char* ws = (char*)d_ws;
    size_t off = 0;
    auto alloc = [&](size_t bytes) -> char* {
        char* p = ws + off;
        off = (off + bytes + 255) & ~(size_t)255;
        return p;
    };
    float*  dinv    = (float*)alloc((size_t)N * 4);
    int*    offs    = (int*)alloc((size_t)(N + 1) * 4);
    int*    gstart  = (int*)alloc((size_t)(G + 1) * 4);
    float*  psum    = (float*)alloc((size_t)G * H * 4);
    int*    bcnt    = (int*)alloc(128 * 4);
    int*    boffs   = (int*)alloc(132 * 4);
    int*    bcursor = (int*)alloc(128 * 4);
    ushort* wt1b    = (ushort*)alloc((size_t)H * D * 2);
    ushort* wt2b    = (ushort*)alloc((size_t)H * H * 2);
    int*    csr     = (int*)alloc((size_t)E * 4);
    char*   hbase   = alloc((size_t)N * H * 2 * 2);      // hb0 + hb1
    ushort* hb0     = (ushort*)hbase;
    ushort* hb1     = (ushort*)(hbase + (size_t)N * H * 2);
    int2*   ebuf    = (int2*)hbase;                      // transient alias (dead after sort)
    (void)ws_size; (void)n_in;

    hipMemsetAsync(bcnt, 0, 128 * 4, stream);
    hipMemsetAsync(psum, 0, (size_t)G * H * 4, stream);

    // CSR build
    k_bucket_hist<<<782, 256, 0, stream>>>(ei + E, E, NB, bcnt);
    k_scan_buckets<<<1, 128, 0, stream>>>(bcnt, NB, boffs, bcursor);
    k_bucket_scatter<<<(E + 2047) / 2048, 256, 0, stream>>>(ei, E, NB, bcursor, ebuf);
    k_bucket_sort<<<NB, 256, 0, stream>>>(ebuf, boffs, N, NB, E, offs, dinv, csr);

    k_bounds<<<(N + 255) / 256, 256, 0, stream>>>(batch, N, G, gstart);
    k_cvtW<<<(128 * D + 255) / 256, 256, 0, stream>>>(W1, wt1b, D);
    k_cvtW<<<(128 * H + 255) / 256, 256, 0, stream>>>(W2, wt2b, H);

    int gblocks = (N + 127) / 128;
    // layer 1
    k_gemm_mfma<0><<<gblocks, 256, 0, stream>>>(x, wt1b, dinv, hb0, N, D);
    k_spmm<<<(N + 3) / 4, 256, 0, stream>>>((const uint*)hb0, csr, offs, dinv, b1,
                                            (uint*)hb1, N);
    // layer 2
    k_gemm_mfma<1><<<gblocks, 256, 0, stream>>>(hb1, wt2b, dinv, hb0, N, H);
    k_spmm<<<(N + 3) / 4, 256, 0, stream>>>((const uint*)hb0, csr, offs, dinv, b2,
                                            (uint*)hb1, N);
    // pool
    k_pool<<<G * 8, 64, 0, stream>>>((const uint*)hb1, gstart, psum, G);
    k_div<<<(G * H + 255) / 256, 256, 0, stream>>>(psum, gstart, outp, G * H);
}